// Round 8
// baseline (595.295 us; speedup 1.0000x reference)
//
#include <hip/hip_runtime.h>
#include <stdint.h>

typedef unsigned short u16;
typedef __attribute__((ext_vector_type(8))) short bf16x8;
typedef __attribute__((ext_vector_type(4))) float f32x4;
typedef __attribute__((ext_vector_type(4))) unsigned short us4;

#define ND 6000
#define NT 12000
#define HD 256
#define LSTR 68   // LDS row stride in shorts: 136 B -> 2-way banks (free), 16B-divisible

__device__ __forceinline__ float bf2f(unsigned int u) {
  u = (u & 0xffffu) << 16;
  return __builtin_bit_cast(float, u);
}
__device__ __forceinline__ u16 f2bf(float f) {
  unsigned int x = __builtin_bit_cast(unsigned int, f);
  x += 0x7fffu + ((x >> 16) & 1u);
  return (u16)(x >> 16);
}
__device__ __forceinline__ void tku5(unsigned x, unsigned* tv) {   // sorted-desc insert, pre-checked
  #pragma unroll
  for (int k = 0; k < 5; ++k) {
    if (x > tv[k]) { unsigned ov = tv[k]; tv[k] = x; x = ov; }
  }
}

// --- dtype detector: f32 data read as bf16 low-halves has wild magnitudes ---
__global__ __launch_bounds__(256) void k_detect(const u16* __restrict__ e, int* __restrict__ flag) {
  __shared__ int any;
  if (threadIdx.x == 0) any = 0;
  __syncthreads();
  uint2 u = ((const uint2*)e)[threadIdx.x];
  float v0 = bf2f(u.x), v2 = bf2f(u.y);
  int big = (!(fabsf(v0) <= 1024.0f)) || (!(fabsf(v2) <= 1024.0f));
  if (big) atomicOr(&any, 1);
  __syncthreads();
  if (threadIdx.x == 0) flag[0] = any;
}

// fused prep: canon e0/e1 -> ce, canon gw -> cgwh, params, init, rinv. grid 6065
__global__ __launch_bounds__(256) void k_prep(const void* __restrict__ e0, const void* __restrict__ e1,
                                              const void* __restrict__ gw, const void* __restrict__ gb,
                                              const void* __restrict__ aw, const void* __restrict__ ab,
                                              const int* __restrict__ flag,
                                              u16* __restrict__ ce, u16* __restrict__ cgwh,
                                              float* __restrict__ pgb, float* __restrict__ paw,
                                              float* __restrict__ pab, float* __restrict__ rinv,
                                              int* __restrict__ cnt, int* __restrict__ fill,
                                              float* __restrict__ macc) {
  const int b = blockIdx.x, tid = threadIdx.x;
  const int isf32 = flag[0];
  if (b < 3000) {
    int i = b * 256 + tid;
    const void* src; int li;
    if (i < 384000) { src = e0; li = i; } else { src = e1; li = i - 384000; }
    us4 h;
    if (isf32) {
      float4 v = ((const float4*)src)[li];
      h[0] = f2bf(v.x); h[1] = f2bf(v.y); h[2] = f2bf(v.z); h[3] = f2bf(v.w);
    } else {
      h = ((const us4*)src)[li];
    }
    *(us4*)(ce + (size_t)i * 4) = h;
    if (b < 47) {
      int k = b * 256 + tid;
      if (k < NT) { cnt[k] = 0; fill[k] = 0; }
      if (k < 512) macc[k] = 0.0f;
    }
  } else if (b < 3064) {
    int i = (b - 3000) * 256 + tid;
    us4 h;
    if (isf32) {
      float4 v = ((const float4*)gw)[i];
      h[0] = f2bf(v.x); h[1] = f2bf(v.y); h[2] = f2bf(v.z); h[3] = f2bf(v.w);
    } else {
      h = ((const us4*)gw)[i];
    }
    *(us4*)(cgwh + (size_t)i * 4) = h;
  } else if (b == 3064) {
    if (isf32) {
      pgb[tid] = ((const float*)gb)[tid];
      paw[tid] = ((const float*)aw)[tid];
      if (tid == 0) pab[0] = ((const float*)ab)[0];
    } else {
      pgb[tid] = bf2f(((const u16*)gb)[tid]);
      paw[tid] = bf2f(((const u16*)aw)[tid]);
      if (tid == 0) pab[0] = bf2f(((const u16*)ab)[0]);
    }
  } else {
    int w = tid >> 6, l = tid & 63;
    int node = (b - 3065) * 4 + w;
    int loc = (node < ND) ? node : node - ND;
    const void* basep = (node < ND) ? e0 : e1;
    float f0, f1, f2, f3;
    if (isf32) {
      float4 v = *(const float4*)((const float*)basep + (size_t)loc * HD + l * 4);
      f0 = v.x; f1 = v.y; f2 = v.z; f3 = v.w;
    } else {
      us4 v = *(const us4*)((const u16*)basep + (size_t)loc * HD + l * 4);
      f0 = bf2f(v[0]); f1 = bf2f(v[1]); f2 = bf2f(v[2]); f3 = bf2f(v[3]);
    }
    float s = f0 * f0 + f1 * f1 + f2 * f2 + f3 * f3;
    #pragma unroll
    for (int off = 32; off > 0; off >>= 1) s += __shfl_xor(s, off);
    if (l == 0) rinv[node] = 1.0f / fmaxf(sqrtf(s), 1e-12f);
  }
}

// 128x256-tile bf16 GEMM with fused per-row top-5 epilogue. grid (47, 24, 2).
// wave w owns rows w*32..+32 x all 256 cols (2x16 tiles of 16x16x32). No sim materialization:
// epilogue packs f16 sims into wave-private LDS (staging buffer reuse), per-lane top-5 over
// 128 cols, lane-pair merge -> per-(row, col-block) top-5 keys -> partial[12000][24][5].
__global__ __launch_bounds__(256, 1) void k_gemm(const u16* __restrict__ ce, const float* __restrict__ rinv,
                                                 unsigned* __restrict__ partial) {
  const int bx = blockIdx.x, by = blockIdx.y, pass = blockIdx.z;
  const int tid = threadIdx.x, w = tid >> 6, l = tid & 63, l15 = l & 15, lq = l >> 4;
  const int qce0 = pass ? ND : 0;
  const int cce0 = pass ? 0 : ND;
  const int mbase = bx * 128;
  const int cbase = by * 256;

  __shared__ __align__(16) short AsBs[(128 + 256) * LSTR];
  short* As = AsBs;
  short* Bs = AsBs + 128 * LSTR;
  __shared__ float Rq[128];
  __shared__ float Rc[256];

  {
    int c = cbase + tid; if (c > ND - 1) c = ND - 1;
    Rc[tid] = rinv[cce0 + c];
    if (tid < 128) {
      int r = mbase + tid; if (r > ND - 1) r = ND - 1;
      Rq[tid] = rinv[qce0 + r];
    }
  }

  const int srow = tid >> 3, scol = (tid & 7) * 8;
  const u16* gA[4]; const u16* gB[8];
  #pragma unroll
  for (int s = 0; s < 4; ++s) {
    int ar = mbase + s * 32 + srow; if (ar > ND - 1) ar = ND - 1;
    gA[s] = ce + (size_t)(qce0 + ar) * HD + scol;
  }
  #pragma unroll
  for (int s = 0; s < 8; ++s) {
    int br = cbase + s * 32 + srow; if (br > ND - 1) br = ND - 1;
    gB[s] = ce + (size_t)(cce0 + br) * HD + scol;
  }

  f32x4 acc[2][16];
  #pragma unroll
  for (int rt = 0; rt < 2; ++rt)
    #pragma unroll
    for (int ct = 0; ct < 16; ++ct) acc[rt][ct] = (f32x4){0.f, 0.f, 0.f, 0.f};

  const int wr = w * 32;
  for (int kt = 0; kt < 4; ++kt) {        // BK=64
    #pragma unroll
    for (int s = 0; s < 4; ++s)
      *(int4*)&As[(s * 32 + srow) * LSTR + scol] = *(const int4*)(gA[s] + kt * 64);
    #pragma unroll
    for (int s = 0; s < 8; ++s)
      *(int4*)&Bs[(s * 32 + srow) * LSTR + scol] = *(const int4*)(gB[s] + kt * 64);
    __syncthreads();
    #pragma unroll
    for (int ks = 0; ks < 2; ++ks) {
      bf16x8 a0 = *(const bf16x8*)&As[(wr + l15) * LSTR + ks * 32 + lq * 8];
      bf16x8 a1 = *(const bf16x8*)&As[(wr + 16 + l15) * LSTR + ks * 32 + lq * 8];
      #pragma unroll
      for (int ct = 0; ct < 16; ++ct) {
        bf16x8 b = *(const bf16x8*)&Bs[(ct * 16 + l15) * LSTR + ks * 32 + lq * 8];
        acc[0][ct] = __builtin_amdgcn_mfma_f32_16x16x32_bf16(a0, b, acc[0][ct], 0, 0, 0);
        acc[1][ct] = __builtin_amdgcn_mfma_f32_16x16x32_bf16(a1, b, acc[1][ct], 0, 0, 0);
      }
    }
    __syncthreads();     // also protects the epilogue's reuse of AsBs after kt=3
  }

  // epilogue: wave-private scan region inside dead AsBs (w*4352 shorts, 32 rows x 136 stride)
  u16* scanb = (u16*)AsBs;
  const int so = w * (32 * 136);
  unsigned tv[5] = {0u, 0u, 0u, 0u, 0u};
  const int sr = l & 31, seg = l >> 5;
  #pragma unroll
  for (int h = 0; h < 2; ++h) {
    #pragma unroll
    for (int ct8 = 0; ct8 < 8; ++ct8) {
      int ct = h * 8 + ct8;
      int col = ct * 16 + l15;
      float rc = Rc[col];
      bool cok = (cbase + col) < ND;
      #pragma unroll
      for (int rt = 0; rt < 2; ++rt) {
        #pragma unroll
        for (int r = 0; r < 4; ++r) {
          int row = rt * 16 + lq * 4 + r;   // 0..31 within wave
          float v = cok ? acc[rt][ct][r] * Rq[wr + row] * rc : -65504.0f;
          scanb[so + row * 136 + ct8 * 16 + l15] = __builtin_bit_cast(unsigned short, (_Float16)v);
        }
      }
    }
    __syncthreads();
    // lane scans row (l&31), 64-col segment (l>>5); running top-5 across both halves
    #pragma unroll
    for (int cc = 0; cc < 16; ++cc) {
      us4 q = *(const us4*)&scanb[so + sr * 136 + seg * 64 + cc * 4];
      #pragma unroll
      for (int u = 0; u < 4; ++u) {
        unsigned b = q[u];
        unsigned m = 0x8000u | (0x7fffu & (0u - (b >> 15)));   // monotone f16 map
        int gcol = cbase + h * 128 + seg * 64 + cc * 4 + u;
        unsigned key = ((b ^ m) << 13) | (unsigned)gcol;
        if (key > tv[4]) tku5(key, tv);
      }
    }
    __syncthreads();
  }
  // merge the two 64-col lanes of each row
  unsigned pv[5];
  #pragma unroll
  for (int k = 0; k < 5; ++k) pv[k] = __shfl_xor(tv[k], 32);
  #pragma unroll
  for (int k = 0; k < 5; ++k) if (pv[k] > tv[4]) tku5(pv[k], tv);
  int grow = mbase + wr + sr;
  if (l < 32 && grow < ND) {
    unsigned* dst = partial + (size_t)(pass * ND + grow) * 120 + by * 5;
    #pragma unroll
    for (int k = 0; k < 5; ++k) dst[k] = tv[k];
  }
}

// merge 24x5 per-block candidate keys per row -> approx top-12 -> rl. one wave per row
__global__ __launch_bounds__(256) void k_cand(const unsigned* __restrict__ partial, unsigned* __restrict__ rl) {
  int tid = threadIdx.x, w = tid >> 6, l = tid & 63;
  int n = blockIdx.x * 4 + w;
  const unsigned* p = partial + (size_t)n * 120;
  unsigned t0 = p[l];
  unsigned t1 = (l < 56) ? p[64 + l] : 0u;
  if (t1 > t0) { unsigned tmp = t0; t0 = t1; t1 = tmp; }
  unsigned mine = 0;
  #pragma unroll
  for (int it = 0; it < 12; ++it) {
    unsigned wm = t0;
    #pragma unroll
    for (int off = 32; off > 0; off >>= 1) { unsigned o2 = __shfl_xor(wm, off); wm = (o2 > wm) ? o2 : wm; }
    if (t0 == wm) { t0 = t1; t1 = 0u; }    // keys unique (col field) -> single pop
    if (l == it) mine = wm;
  }
  if (l < 12) rl[n * 12 + l] = mine;
}

// fused: blocks <3000 -> exact f64 re-rank of rl's 12 candidates; blocks >=3000 -> xw GEMM
__global__ __launch_bounds__(256, 1) void k_xwex(const void* __restrict__ e0raw, const void* __restrict__ e1raw,
                                                 const unsigned* __restrict__ rl, const int* __restrict__ flag,
                                                 int* __restrict__ edst, int* __restrict__ cnt,
                                                 const u16* __restrict__ ce, const u16* __restrict__ gwh,
                                                 u16* __restrict__ xwb) {
  const int tid = threadIdx.x, w = tid >> 6, l = tid & 63;
  if (blockIdx.x < 3000) {
    int n = blockIdx.x * 4 + w;
    const int isf32 = flag[0];
    int qloc = (n < ND) ? n : n - ND;
    const void* qb = (n < ND) ? e0raw : e1raw;
    double q0, q1, q2, q3;
    if (isf32) {
      float4 v = *(const float4*)((const float*)qb + (size_t)qloc * HD + l * 4);
      q0 = v.x; q1 = v.y; q2 = v.z; q3 = v.w;
    } else {
      us4 v = *(const us4*)((const u16*)qb + (size_t)qloc * HD + l * 4);
      q0 = bf2f(v[0]); q1 = bf2f(v[1]); q2 = bf2f(v[2]); q3 = bf2f(v[3]);
    }
    double dv[12]; int di[12];
    #pragma unroll
    for (int c = 0; c < 12; ++c) {
      unsigned key = rl[n * 12 + c];
      int gcol = (int)(key & 8191u);
      int cid = (key != 0u && gcol < ND) ? ((n < ND) ? ND + gcol : gcol) : -1;
      int cidc = (cid < 0) ? 0 : cid;
      int cloc = (cidc < ND) ? cidc : cidc - ND;
      const void* cb = (cidc < ND) ? e0raw : e1raw;
      double c0, c1, c2, c3;
      if (isf32) {
        float4 v = *(const float4*)((const float*)cb + (size_t)cloc * HD + l * 4);
        c0 = v.x; c1 = v.y; c2 = v.z; c3 = v.w;
      } else {
        us4 v = *(const us4*)((const u16*)cb + (size_t)cloc * HD + l * 4);
        c0 = bf2f(v[0]); c1 = bf2f(v[1]); c2 = bf2f(v[2]); c3 = bf2f(v[3]);
      }
      double dot = q0 * c0 + q1 * c1 + q2 * c2 + q3 * c3;
      double nrm = c0 * c0 + c1 * c1 + c2 * c2 + c3 * c3;
      #pragma unroll
      for (int off = 32; off > 0; off >>= 1) {
        dot += __shfl_xor(dot, off);
        nrm += __shfl_xor(nrm, off);
      }
      dv[c] = (cid < 0) ? -1e300 : dot / sqrt(nrm);
      di[c] = cid;
    }
    if (l == 0) {
      double tv5[5]; int ti5[5];
      #pragma unroll
      for (int k = 0; k < 5; ++k) { tv5[k] = -1e300; ti5[k] = -1; }
      #pragma unroll
      for (int c = 0; c < 12; ++c) {
        double x = dv[c]; int id = di[c];
        #pragma unroll
        for (int k = 0; k < 5; ++k) {
          if (x > tv5[k]) { double ov = tv5[k]; int oi = ti5[k]; tv5[k] = x; ti5[k] = id; x = ov; id = oi; }
        }
      }
      #pragma unroll
      for (int k = 0; k < 5; ++k) {
        int d = (ti5[k] >= 0 && tv5[k] > 0.0) ? ti5[k] : -1;
        edst[n * 5 + k] = d;
        if (d >= 0) atomicAdd(&cnt[d], 1);
      }
    }
  } else {
    int b2 = blockIdx.x - 3000;
    int bxw = b2 % 188, byw = b2 / 188;
    int l15 = l & 15, lq = l >> 4;
    int m0 = bxw * 64 + w * 16 + l15;
    int mc = (m0 < NT) ? m0 : NT - 1;
    const u16* arow = ce + (size_t)mc * HD;
    bf16x8 afr[8];
    #pragma unroll
    for (int ks = 0; ks < 8; ++ks) afr[ks] = *(const bf16x8*)(arow + ks * 32 + lq * 8);
    int hbase = byw * 64;
    for (int ct = 0; ct < 4; ++ct) {
      f32x4 acc = {0.f, 0.f, 0.f, 0.f};
      const u16* brow = gwh + (size_t)(hbase + ct * 16 + l15) * HD;
      #pragma unroll
      for (int ks = 0; ks < 8; ++ks) {
        bf16x8 b = *(const bf16x8*)(brow + ks * 32 + lq * 8);
        acc = __builtin_amdgcn_mfma_f32_16x16x32_bf16(afr[ks], b, acc, 0, 0, 0);
      }
      #pragma unroll
      for (int r = 0; r < 4; ++r) {
        int m = bxw * 64 + w * 16 + lq * 4 + r;
        if (m < NT) xwb[(size_t)m * HD + hbase + ct * 16 + l15] = f2bf(acc[r]);
      }
    }
  }
}

// single-block prefix scan: 12 elems/thread, wave shuffle scans
__global__ __launch_bounds__(1024, 1) void k_scan(const int* __restrict__ cnt,
                                                  int* __restrict__ coff, float* __restrict__ dinv) {
  __shared__ int wsum[16];
  int tid = threadIdx.x;
  int lane = tid & 63, wv = tid >> 6;
  int base = tid * 12;
  bool act = base < NT;
  int v[12]; int s = 0;
  #pragma unroll
  for (int j = 0; j < 12; ++j) { v[j] = act ? cnt[base + j] : 0; s += v[j]; }
  int si = s;
  #pragma unroll
  for (int off = 1; off < 64; off <<= 1) { int t2 = __shfl_up(si, off); if (lane >= off) si += t2; }
  if (lane == 63) wsum[wv] = si;
  __syncthreads();
  if (wv == 0) {
    int x = (lane < 16) ? wsum[lane] : 0;
    #pragma unroll
    for (int off = 1; off < 16; off <<= 1) { int t2 = __shfl_up(x, off); if (lane >= off) x += t2; }
    if (lane < 16) wsum[lane] = x;
  }
  __syncthreads();
  int wpre = (wv > 0) ? wsum[wv - 1] : 0;
  int excl = wpre + si - s;
  if (act) {
    #pragma unroll
    for (int j = 0; j < 12; ++j) {
      coff[base + j] = excl;
      dinv[base + j] = 1.0f / sqrtf(1.0f + (float)v[j]);
      excl += v[j];
    }
  }
  if (tid == 0) coff[NT] = wsum[15];
}

// parallel CSR fill (235 blocks — serializing this onto one block cost 224 us in R7)
__global__ __launch_bounds__(256) void k_fill(const int* __restrict__ edst, const int* __restrict__ coff,
                                              int* __restrict__ fill, int* __restrict__ cedge) {
  int s = blockIdx.x * 256 + threadIdx.x;
  if (s >= NT * 5) return;
  int d = edst[s];
  if (d < 0) return;
  int n = s / 5;
  int p = atomicAdd(&fill[d], 1);
  cedge[coff[d] + p] = n;
}

// GCN gather + attention + dtype-correct store + f32 domain-mean accumulation
__global__ __launch_bounds__(256, 1) void k_gather(const void* __restrict__ e0raw, const void* __restrict__ e1raw,
                                                   const u16* __restrict__ xwb, const float* __restrict__ dinv,
                                                   const int* __restrict__ coff, const int* __restrict__ cedge,
                                                   const float* __restrict__ pgb, const float* __restrict__ paw,
                                                   const float* __restrict__ pab, const int* __restrict__ flag,
                                                   void* __restrict__ outp, float* __restrict__ macc) {
  int tid = threadIdx.x, w = tid >> 6, l = tid & 63;
  const int isf32 = flag[0];
  float4 b4 = ((const float4*)pgb)[l];
  float4 a4 = ((const float4*)paw)[l];
  float ab = pab[0];
  __shared__ float bacc[256];
  bacc[tid] = 0.0f;
  __syncthreads();
  float sum0 = 0.f, sum1 = 0.f, sum2 = 0.f, sum3 = 0.f;
  int nodeBase = blockIdx.x * 16 + w * 4;
  for (int nn = 0; nn < 4; ++nn) {
    int t = nodeBase + nn;
    float dt = dinv[t];
    int o0 = coff[t], o1 = coff[t + 1];
    float g0 = 0.f, g1 = 0.f, g2 = 0.f, g3 = 0.f;
    for (int e = o0; e < o1; ++e) {
      int s = cedge[e];
      float ds = dinv[s];
      us4 xv = *(const us4*)(xwb + (size_t)s * HD + l * 4);
      g0 += ds * bf2f(xv[0]); g1 += ds * bf2f(xv[1]);
      g2 += ds * bf2f(xv[2]); g3 += ds * bf2f(xv[3]);
    }
    us4 xt = *(const us4*)(xwb + (size_t)t * HD + l * 4);
    g0 = dt * g0 + dt * dt * bf2f(xt[0]) + b4.x;
    g1 = dt * g1 + dt * dt * bf2f(xt[1]) + b4.y;
    g2 = dt * g2 + dt * dt * bf2f(xt[2]) + b4.z;
    g3 = dt * g3 + dt * dt * bf2f(xt[3]) + b4.w;
    int loc = (t < ND) ? t : t - ND;
    const void* ebase = (t < ND) ? e0raw : e1raw;
    float e4_0, e4_1, e4_2, e4_3;
    if (isf32) {
      float4 ev = *(const float4*)((const float*)ebase + (size_t)loc * HD + l * 4);
      e4_0 = ev.x; e4_1 = ev.y; e4_2 = ev.z; e4_3 = ev.w;
    } else {
      us4 ue = *(const us4*)((const u16*)ebase + (size_t)loc * HD + l * 4);
      e4_0 = bf2f(ue[0]); e4_1 = bf2f(ue[1]); e4_2 = bf2f(ue[2]); e4_3 = bf2f(ue[3]);
    }
    float s0 = e4_0 * a4.x + e4_1 * a4.y + e4_2 * a4.z + e4_3 * a4.w;
    float s1 = g0 * a4.x + g1 * a4.y + g2 * a4.z + g3 * a4.w;
    #pragma unroll
    for (int off = 32; off > 0; off >>= 1) { s0 += __shfl_xor(s0, off); s1 += __shfl_xor(s1, off); }
    s0 += ab; s1 += ab;
    float m = fmaxf(s0, s1);
    float p0 = __expf(s0 - m), p1 = __expf(s1 - m);
    float iz = 1.0f / (p0 + p1);
    float w0 = p0 * iz, w1 = p1 * iz;
    float u0 = w0 * e4_0 + w1 * g0;
    float u1 = w0 * e4_1 + w1 * g1;
    float u2 = w0 * e4_2 + w1 * g2;
    float u3 = w0 * e4_3 + w1 * g3;
    size_t ob = 1 + (size_t)t * HD + l * 4;
    if (isf32) {
      float* o = (float*)outp;
      o[ob + 0] = u0; o[ob + 1] = u1; o[ob + 2] = u2; o[ob + 3] = u3;
    } else {
      u16* o = (u16*)outp;
      o[ob + 0] = f2bf(u0); o[ob + 1] = f2bf(u1); o[ob + 2] = f2bf(u2); o[ob + 3] = f2bf(u3);
    }
    sum0 += u0; sum1 += u1; sum2 += u2; sum3 += u3;
  }
  atomicAdd(&bacc[l * 4 + 0], sum0);
  atomicAdd(&bacc[l * 4 + 1], sum1);
  atomicAdd(&bacc[l * 4 + 2], sum2);
  atomicAdd(&bacc[l * 4 + 3], sum3);
  __syncthreads();
  int dom = (blockIdx.x < 375) ? 0 : 1;
  atomicAdd(&macc[dom * 256 + tid], bacc[tid]);
}

__global__ __launch_bounds__(256) void k_loss(const float* __restrict__ macc, const int* __restrict__ flag,
                                              void* __restrict__ outp) {
  int tid = threadIdx.x;
  float d = (macc[tid] - macc[256 + tid]) * (1.0f / (float)ND);
  float v = d * d;
  #pragma unroll
  for (int off = 32; off > 0; off >>= 1) v += __shfl_xor(v, off);
  __shared__ float rr[4];
  if ((tid & 63) == 0) rr[tid >> 6] = v;
  __syncthreads();
  if (tid == 0) {
    float loss = rr[0] + rr[1] + rr[2] + rr[3];
    if (flag[0]) ((float*)outp)[0] = loss;
    else ((u16*)outp)[0] = f2bf(loss);
  }
}

extern "C" void kernel_launch(void* const* d_in, const int* in_sizes, int n_in,
                              void* d_out, int out_size, void* d_ws, size_t ws_size,
                              hipStream_t stream) {
  const void* e0 = d_in[2];
  const void* e1 = d_in[3];
  const void* gw = d_in[8];
  const void* gb = d_in[9];
  const void* aw = d_in[10];
  const void* abp = d_in[11];

  float* wsf = (float*)d_ws;   // offsets in 4-byte slots
  size_t o = 0;
  int*      flag = (int*)(wsf + o); o += 4;
  u16*      ce   = (u16*)(wsf + o); o += 1536000;   // 12000x256 bf16
  u16*      cgwh = (u16*)(wsf + o); o += 32768;     // 256x256 bf16
  float*    pgb  = wsf + o; o += 256;
  float*    paw  = wsf + o; o += 256;
  float*    pab  = wsf + o; o += 8;
  float*    rinv = wsf + o; o += 12032;
  unsigned* rl   = (unsigned*)(wsf + o); o += 144000;  // 12000 x 12 candidate keys
  int*      edst = (int*)(wsf + o); o += 60000;
  int*      cnt  = (int*)(wsf + o); o += 12000;
  int*      fill = (int*)(wsf + o); o += 12000;
  int*      coff = (int*)(wsf + o); o += 12008;
  int*      cedge = (int*)(wsf + o); o += 60000;
  float*    macc = wsf + o; o += 512;
  float*    dinv = wsf + o; o += 12000;
  unsigned* partial = (unsigned*)(wsf + o); o += 1440000;  // 12000 x 24 x 5 keys
  u16*      xwb = (u16*)partial;                // overlay: written after k_cand consumes partial
  (void)in_sizes; (void)n_in; (void)out_size; (void)ws_size;   // total ~13.3 MiB (<= 14.5 proven)

  k_detect<<<1, 256, 0, stream>>>((const u16*)e0, flag);
  k_prep<<<6065, 256, 0, stream>>>(e0, e1, gw, gb, aw, abp, flag, ce, cgwh, pgb, paw, pab,
                                   rinv, cnt, fill, macc);
  k_gemm<<<dim3(47, 24, 2), 256, 0, stream>>>(ce, rinv, partial);
  k_cand<<<3000, 256, 0, stream>>>(partial, rl);
  k_xwex<<<3752, 256, 0, stream>>>(e0, e1, rl, flag, edst, cnt, ce, cgwh, xwb);
  k_scan<<<1, 1024, 0, stream>>>(cnt, coff, dinv);
  k_fill<<<235, 256, 0, stream>>>(edst, coff, fill, cedge);
  k_gather<<<750, 256, 0, stream>>>(e0, e1, xwb, dinv, coff, cedge, pgb, paw, pab, flag, d_out, macc);
  k_loss<<<1, 256, 0, stream>>>(macc, flag, d_out);
}